// Round 5
// baseline (606.015 us; speedup 1.0000x reference)
//
#include <hip/hip_runtime.h>
#include <math.h>

// Problem constants (fixed by the reference)
#define NB 8
#define SEQ 2048
#define HID 64
#define HDIM 32
#define ROWS (NB * SEQ)            // 16384
#define OUT_ELEMS (ROWS * HID)     // 1048576 floats (the `out` tensor)
// QSCALE = log2(e) / sqrt(32): folds softmax scale AND exp->exp2 conversion into q.
#define QSCALE 0.25503486f

// INSTRUMENTATION ROUND: attn + qkv bodies run REP times (identical math,
// idempotent stores) so the attn dispatch exceeds the ~160us harness fills
// and surfaces in rocprof's top-5 with full counters. Revert REP to 1 after.
#define REP 2

typedef __attribute__((ext_vector_type(8))) short bf16x8;
typedef __attribute__((ext_vector_type(4))) float f32x4;

__device__ __forceinline__ ushort f2bf(float f) {          // f32 -> bf16 RNE
    uint u = __builtin_bit_cast(uint, f);
    u += 0x7FFFu + ((u >> 16) & 1u);
    return (ushort)(u >> 16);
}
__device__ __forceinline__ float bf2f(ushort h) {
    uint u = ((uint)h) << 16;
    return __builtin_bit_cast(float, u);
}

// ---------------------------------------------------------------------------
// Kernel 1: fused QKV projection + bf16 hi/lo split + V transpose.
// ---------------------------------------------------------------------------
__global__ __launch_bounds__(256, 1)
void qkv_proj_kernel(const float* __restrict__ hs, const float* __restrict__ qx,
                     const float* __restrict__ Wq, const float* __restrict__ bq,
                     const float* __restrict__ Wk, const float* __restrict__ bk,
                     const float* __restrict__ Wv, const float* __restrict__ bv,
                     ushort* __restrict__ q_hi, ushort* __restrict__ q_lo,
                     ushort* __restrict__ k_hi, ushort* __restrict__ k_lo,
                     ushort* __restrict__ vt_hi, ushort* __restrict__ vt_lo)
{
    __shared__ __align__(16) float xq_lds[64][64];  // broadcast-read only
    __shared__ __align__(16) float xh_lds[64][64];
    __shared__ float vbuf[64][65];                  // +1 pad for transpose reads

    const int t  = threadIdx.x;
    const int r0 = blockIdx.x * 64;
    const int b  = r0 >> 11;            // 64-row block never crosses a batch

#pragma unroll 1
    for (int rep = 0; rep < REP; ++rep) {
#pragma unroll
    for (int u = 0; u < 4; ++u) {
        const int idx = t + 256 * u;            // float4 index 0..1023
        const int rr = idx >> 4, kk = (idx & 15) * 4;
        *(float4*)&xq_lds[rr][kk] = *(const float4*)(qx + (size_t)(r0 + rr) * HID + kk);
        *(float4*)&xh_lds[rr][kk] = *(const float4*)(hs + (size_t)(r0 + rr) * HID + kk);
    }
    __syncthreads();

    const int c = t & 63, w = t >> 6;
    const int rw = w * 16;                        // wave's 16 rows
    const int h = c >> 5, d = c & 31;
    const size_t obase = ((size_t)((b * 2 + h) * SEQ) + (r0 & 2047) + rw) * 32 + d;

    // ---------------- phase Q ----------------
    {
        float4 wr[16];
#pragma unroll
        for (int i = 0; i < 16; ++i) wr[i] = *(const float4*)(Wq + c * 64 + 4 * i);
        const float bc = bq[c];
        f32x4 acc[16];
#pragma unroll
        for (int r = 0; r < 16; ++r) acc[r] = (f32x4){0.f, 0.f, 0.f, 0.f};
#pragma unroll
        for (int k4 = 0; k4 < 16; ++k4) {
#pragma unroll
            for (int r = 0; r < 16; ++r) {
                const float4 x4 = *(const float4*)&xq_lds[rw + r][k4 * 4];  // bcast
                acc[r][0] += x4.x * wr[k4].x; acc[r][1] += x4.y * wr[k4].y;
                acc[r][2] += x4.z * wr[k4].z; acc[r][3] += x4.w * wr[k4].w;
            }
        }
#pragma unroll
        for (int r = 0; r < 16; ++r) {
            const float v = (acc[r][0] + acc[r][1] + acc[r][2] + acc[r][3] + bc) * QSCALE;
            const ushort hv = f2bf(v);
            q_hi[obase + (size_t)r * 32] = hv;
            q_lo[obase + (size_t)r * 32] = f2bf(v - bf2f(hv));
        }
    }
    // ---------------- phase K ----------------
    {
        float4 wr[16];
#pragma unroll
        for (int i = 0; i < 16; ++i) wr[i] = *(const float4*)(Wk + c * 64 + 4 * i);
        const float bc = bk[c];
        f32x4 acc[16];
#pragma unroll
        for (int r = 0; r < 16; ++r) acc[r] = (f32x4){0.f, 0.f, 0.f, 0.f};
#pragma unroll
        for (int k4 = 0; k4 < 16; ++k4) {
#pragma unroll
            for (int r = 0; r < 16; ++r) {
                const float4 x4 = *(const float4*)&xh_lds[rw + r][k4 * 4];
                acc[r][0] += x4.x * wr[k4].x; acc[r][1] += x4.y * wr[k4].y;
                acc[r][2] += x4.z * wr[k4].z; acc[r][3] += x4.w * wr[k4].w;
            }
        }
#pragma unroll
        for (int r = 0; r < 16; ++r) {
            const float v = acc[r][0] + acc[r][1] + acc[r][2] + acc[r][3] + bc;
            const ushort hv = f2bf(v);
            k_hi[obase + (size_t)r * 32] = hv;
            k_lo[obase + (size_t)r * 32] = f2bf(v - bf2f(hv));
        }
    }
    // ---------------- phase V ----------------
    {
        float4 wr[16];
#pragma unroll
        for (int i = 0; i < 16; ++i) wr[i] = *(const float4*)(Wv + c * 64 + 4 * i);
        const float bc = bv[c];
        f32x4 acc[16];
#pragma unroll
        for (int r = 0; r < 16; ++r) acc[r] = (f32x4){0.f, 0.f, 0.f, 0.f};
#pragma unroll
        for (int k4 = 0; k4 < 16; ++k4) {
#pragma unroll
            for (int r = 0; r < 16; ++r) {
                const float4 x4 = *(const float4*)&xq_lds[rw + r][k4 * 4];  // v uses qx!
                acc[r][0] += x4.x * wr[k4].x; acc[r][1] += x4.y * wr[k4].y;
                acc[r][2] += x4.z * wr[k4].z; acc[r][3] += x4.w * wr[k4].w;
            }
        }
#pragma unroll
        for (int r = 0; r < 16; ++r)
            vbuf[rw + r][c] = acc[r][0] + acc[r][1] + acc[r][2] + acc[r][3] + bc;
    }
    __syncthreads();

    // V transpose: lane c -> (h2,d2) column; 2 groups of 8 consecutive rows
#pragma unroll
    for (int g = 0; g < 2; ++g) {
        const int row8 = (g * 4 + w) * 8;
        bf16x8 hi8, lo8;
#pragma unroll
        for (int e = 0; e < 8; ++e) {
            const float v = vbuf[row8 + e][c];
            const ushort hv = f2bf(v);
            hi8[e] = (short)hv;
            lo8[e] = (short)f2bf(v - bf2f(hv));
        }
        const size_t vo = ((size_t)((b * 2 + h) * 32) + d) * SEQ + (r0 & 2047) + row8;
        *reinterpret_cast<bf16x8*>(vt_hi + vo) = hi8;
        *reinterpret_cast<bf16x8*>(vt_lo + vo) = lo8;
    }
    }  // rep
}

// ---------------------------------------------------------------------------
// Kernel 2 (v4 + REP): fused attention, 64-row blocks, col-quarter waves.
// Identical math to round 4, executed REP times for counter visibility.
// ---------------------------------------------------------------------------
__global__ __launch_bounds__(256, 3)
void attn_kernel(const ushort* __restrict__ q_hi, const ushort* __restrict__ q_lo,
                 const ushort* __restrict__ k_hi, const ushort* __restrict__ k_lo,
                 const ushort* __restrict__ vt_hi, const ushort* __restrict__ vt_lo,
                 float* __restrict__ d_out)
{
    __shared__ float z_buf[4][64];
    __shared__ __align__(16) float ctx_buf[4][64][32];       // 32 KB
    __shared__ __align__(16) ushort pbuf[16][512];           // 16 KB: [w*4+rt]

    // XCD-aware swizzle: 512 blocks -> 64 consecutive per XCD
    const int bid   = blockIdx.x;
    const int swz   = (bid & 7) * 64 + (bid >> 3);
    const int slice = swz >> 5;          // 0..15 == b*2 + h
    const int qb    = swz & 31;
    const int bb = slice >> 1, hh = slice & 1;
    const int q0 = qb * 64;

    const int tid  = threadIdx.x;
    const int w    = tid >> 6, lane = tid & 63;
    const int lg   = lane >> 4, li = lane & 15;   // frag: i/j = li, k = 8*lg+e
    const int cq0  = w * 512;                     // wave's column quarter

    // A-fragments (q) for the block's 4 row-tiles
    bf16x8 aqh[4], aql[4];
#pragma unroll
    for (int rt = 0; rt < 4; ++rt) {
        const size_t qoff = ((size_t)slice * SEQ + q0 + rt * 16 + li) * 32 + lg * 8;
        aqh[rt] = *reinterpret_cast<const bf16x8*>(q_hi + qoff);
        aql[rt] = *reinterpret_cast<const bf16x8*>(q_lo + qoff);
    }

    const size_t kbase = (size_t)slice * SEQ * 32;

#pragma unroll 1
    for (int rep = 0; rep < REP; ++rep) {
    // ------------------- pass 1: row sums Z (hi*hi only) -------------------
    float zacc[16];
#pragma unroll
    for (int i = 0; i < 16; ++i) zacc[i] = 0.f;
#pragma unroll 2
    for (int ct = 0; ct < 32; ++ct) {
        const int col0 = cq0 + ct * 16;
        const size_t ko = kbase + (size_t)(col0 + li) * 32 + lg * 8;
        const bf16x8 bh = *reinterpret_cast<const bf16x8*>(k_hi + ko);
        f32x4 acc[4];
#pragma unroll
        for (int rt = 0; rt < 4; ++rt) {
            acc[rt] = (f32x4){0.f, 0.f, 0.f, 0.f};
            acc[rt] = __builtin_amdgcn_mfma_f32_16x16x32_bf16(aqh[rt], bh, acc[rt], 0, 0, 0);
        }
#pragma unroll
        for (int rt = 0; rt < 4; ++rt)
#pragma unroll
            for (int r = 0; r < 4; ++r)
                zacc[rt * 4 + r] += __builtin_amdgcn_exp2f(acc[rt][r]);
    }
#pragma unroll
    for (int m = 1; m < 16; m <<= 1) {
#pragma unroll
        for (int i = 0; i < 16; ++i) zacc[i] += __shfl_xor(zacc[i], m, 64);
    }
    if (li == 0) {
#pragma unroll
        for (int rt = 0; rt < 4; ++rt)
#pragma unroll
            for (int r = 0; r < 4; ++r)
                z_buf[w][rt * 16 + lg * 4 + r] = zacc[rt * 4 + r];
    }
    __syncthreads();
    float rcpz[16];
#pragma unroll
    for (int rt = 0; rt < 4; ++rt)
#pragma unroll
        for (int r = 0; r < 4; ++r) {
            const int row = rt * 16 + lg * 4 + r;
            rcpz[rt * 4 + r] = 1.0f / (z_buf[0][row] + z_buf[1][row] +
                                       z_buf[2][row] + z_buf[3][row]);
        }

    // ------------------- pass 2: probs + PV -------------------
    f32x4 pacc[4][2];
#pragma unroll
    for (int rt = 0; rt < 4; ++rt)
#pragma unroll
        for (int dt = 0; dt < 2; ++dt) pacc[rt][dt] = (f32x4){0.f, 0.f, 0.f, 0.f};

    float* probs = d_out + OUT_ELEMS + ((size_t)slice * SEQ + q0) * SEQ;

#pragma unroll 1
    for (int c2 = 0; c2 < 16; ++c2) {          // 32-col chunks in the quarter
#pragma unroll
        for (int half = 0; half < 2; ++half) {
            const int col0 = cq0 + c2 * 32 + half * 16;
            const size_t ko = kbase + (size_t)(col0 + li) * 32 + lg * 8;
            const bf16x8 bh = *reinterpret_cast<const bf16x8*>(k_hi + ko);
            const bf16x8 bl = *reinterpret_cast<const bf16x8*>(k_lo + ko);
#pragma unroll
            for (int rt = 0; rt < 4; ++rt) {
                f32x4 acc = {0.f, 0.f, 0.f, 0.f};
                acc = __builtin_amdgcn_mfma_f32_16x16x32_bf16(aqh[rt], bh, acc, 0, 0, 0);
                acc = __builtin_amdgcn_mfma_f32_16x16x32_bf16(aql[rt], bh, acc, 0, 0, 0);
                acc = __builtin_amdgcn_mfma_f32_16x16x32_bf16(aqh[rt], bl, acc, 0, 0, 0);
                ushort* pb = &pbuf[w * 4 + rt][0];
#pragma unroll
                for (int r = 0; r < 4; ++r) {
                    const float p = __builtin_amdgcn_exp2f(acc[r]) * rcpz[rt * 4 + r];
                    const int row = lg * 4 + r;
                    probs[(size_t)(rt * 16 + row) * SEQ + col0 + li] = p;
                    const int cc = half * 16 + li;
                    pb[row * 32 + (((cc >> 3) ^ lg) & 3) * 8 + (cc & 7)] = f2bf(p);
                }
            }
        }
        // PV for this 32-col chunk; V frags loaded once, reused across 4 rt
        const int j0 = cq0 + c2 * 32;
        bf16x8 ap[4];
#pragma unroll
        for (int rt = 0; rt < 4; ++rt)
            ap[rt] = *reinterpret_cast<const bf16x8*>(
                &pbuf[w * 4 + rt][li * 32 + (((lg ^ (li >> 2)) & 3) * 8)]);
#pragma unroll
        for (int dt = 0; dt < 2; ++dt) {
            const size_t vo = ((size_t)slice * 32 + dt * 16 + li) * SEQ + j0 + lg * 8;
            const bf16x8 bvh = *reinterpret_cast<const bf16x8*>(vt_hi + vo);
            const bf16x8 bvl = *reinterpret_cast<const bf16x8*>(vt_lo + vo);
#pragma unroll
            for (int rt = 0; rt < 4; ++rt) {
                pacc[rt][dt] = __builtin_amdgcn_mfma_f32_16x16x32_bf16(ap[rt], bvh, pacc[rt][dt], 0, 0, 0);
                pacc[rt][dt] = __builtin_amdgcn_mfma_f32_16x16x32_bf16(ap[rt], bvl, pacc[rt][dt], 0, 0, 0);
            }
        }
    }

    // partials -> LDS, cross-wave (col-quarter) reduce, write ctx
#pragma unroll
    for (int rt = 0; rt < 4; ++rt)
#pragma unroll
        for (int dt = 0; dt < 2; ++dt)
#pragma unroll
            for (int r = 0; r < 4; ++r)
                ctx_buf[w][rt * 16 + lg * 4 + r][dt * 16 + li] = pacc[rt][dt][r];
    __syncthreads();
#pragma unroll
    for (int u = 0; u < 2; ++u) {
        const int idx4 = tid * 2 + u;            // float4 cell 0..511
        const int row = idx4 >> 3, dq = idx4 & 7;
        float4 s = *reinterpret_cast<const float4*>(&ctx_buf[0][row][dq * 4]);
#pragma unroll
        for (int ww = 1; ww < 4; ++ww) {
            const float4 c = *reinterpret_cast<const float4*>(&ctx_buf[ww][row][dq * 4]);
            s.x += c.x; s.y += c.y; s.z += c.z; s.w += c.w;
        }
        *reinterpret_cast<float4*>(
            d_out + ((size_t)bb * SEQ + q0 + row) * HID + hh * HDIM + dq * 4) = s;
    }
    __syncthreads();   // ctx_buf fully consumed before next rep rewrites it
    }  // rep
}

// ---------------------------------------------------------------------------
// Kernel 3: output projection, in place over d_out's ctx region.
// (NOT repped: in-place, not idempotent.)
// ---------------------------------------------------------------------------
__global__ __launch_bounds__(256, 1)
void out_proj_kernel(const float* __restrict__ Wo, const float* __restrict__ bo,
                     float* __restrict__ out)
{
    const int c    = threadIdx.x & 63;
    const int rloc = threadIdx.x >> 6;

    float4 wo[16];
#pragma unroll
    for (int i = 0; i < 16; ++i) wo[i] = *(const float4*)(Wo + c * 64 + 4 * i);
    const float boc = bo[c];

    for (int rg = blockIdx.x; rg < ROWS / 4; rg += gridDim.x) {
        const int row = rg * 4 + rloc;
        const float* x = out + (size_t)row * HID;  // ctx row (wave-uniform addr)
        float a = 0.f;
#pragma unroll
        for (int i = 0; i < 16; ++i) {
            const float4 x4 = *(const float4*)(x + 4 * i);
            a += x4.x * wo[i].x + x4.y * wo[i].y + x4.z * wo[i].z + x4.w * wo[i].w;
        }
        out[(size_t)row * HID + c] = a + boc;
    }
}

// ---------------------------------------------------------------------------
extern "C" void kernel_launch(void* const* d_in, const int* in_sizes, int n_in,
                              void* d_out, int out_size, void* d_ws, size_t ws_size,
                              hipStream_t stream)
{
    const float* hs = (const float*)d_in[0];
    const float* qx = (const float*)d_in[1];
    const float* Wq = (const float*)d_in[2];
    const float* bq = (const float*)d_in[3];
    const float* Wk = (const float*)d_in[4];
    const float* bk = (const float*)d_in[5];
    const float* Wv = (const float*)d_in[6];
    const float* bv = (const float*)d_in[7];
    const float* Wo = (const float*)d_in[8];
    const float* bo = (const float*)d_in[9];
    float* out = (float*)d_out;

    // workspace: 6 bf16 arrays of 16*2048*32 = 1M elements (2 MB) each = 12 MB
    const size_t N = (size_t)16 * SEQ * 32;
    ushort* q_hi  = (ushort*)d_ws;
    ushort* q_lo  = q_hi + N;
    ushort* k_hi  = q_lo + N;
    ushort* k_lo  = k_hi + N;
    ushort* vt_hi = k_lo + N;
    ushort* vt_lo = vt_hi + N;

    qkv_proj_kernel<<<256, 256, 0, stream>>>(hs, qx, Wq, bq, Wk, bk, Wv, bv,
                                             q_hi, q_lo, k_hi, k_lo, vt_hi, vt_lo);
    attn_kernel<<<512, 256, 0, stream>>>(q_hi, q_lo, k_hi, k_lo, vt_hi, vt_lo, out);
    out_proj_kernel<<<512, 256, 0, stream>>>(Wo, bo, out);
}

// Round 6
// 105.919 us; speedup vs baseline: 5.7215x; 5.7215x over previous
//
#include <hip/hip_runtime.h>
#include <math.h>

// Problem constants (fixed by the reference)
#define NB 8
#define SEQ 2048
#define HID 64
#define HDIM 32
#define ROWS (NB * SEQ)            // 16384
#define OUT_ELEMS (ROWS * HID)     // 1048576 floats (the `out` tensor)
// QSCALE = log2(e) / sqrt(32): folds softmax scale AND exp->exp2 conversion into q.
#define QSCALE 0.25503486f

typedef __attribute__((ext_vector_type(8))) short bf16x8;
typedef __attribute__((ext_vector_type(4))) float f32x4;
typedef __attribute__((ext_vector_type(4))) uint u32x4;

__device__ __forceinline__ ushort f2bf(float f) {          // f32 -> bf16 RNE
    uint u = __builtin_bit_cast(uint, f);
    u += 0x7FFFu + ((u >> 16) & 1u);
    return (ushort)(u >> 16);
}
__device__ __forceinline__ float bf2f(ushort h) {
    uint u = ((uint)h) << 16;
    return __builtin_bit_cast(float, u);
}
__device__ __forceinline__ uint cvt_pk_bf16(float lo, float hi) {  // RNE pack
    uint r;
    asm("v_cvt_pk_bf16_f32 %0, %1, %2" : "=v"(r) : "v"(lo), "v"(hi));
    return r;
}

// ---------------------------------------------------------------------------
// Kernel 1: fused QKV projection + bf16 split + V transpose.
// q: hi+lo split (scaled by QSCALE). k, v: hi only (error analysis: bf16 RNE
// on k/v gives ~4e-4 relative on probs / ~5e-5 on ctx — far under threshold).
// ---------------------------------------------------------------------------
__global__ __launch_bounds__(256, 1)
void qkv_proj_kernel(const float* __restrict__ hs, const float* __restrict__ qx,
                     const float* __restrict__ Wq, const float* __restrict__ bq,
                     const float* __restrict__ Wk, const float* __restrict__ bk,
                     const float* __restrict__ Wv, const float* __restrict__ bv,
                     ushort* __restrict__ q_hi, ushort* __restrict__ q_lo,
                     ushort* __restrict__ k_hi, ushort* __restrict__ vt_hi)
{
    __shared__ __align__(16) float xq_lds[64][64];  // broadcast-read only
    __shared__ __align__(16) float xh_lds[64][64];
    __shared__ float vbuf[64][65];                  // +1 pad for transpose reads

    const int t  = threadIdx.x;
    const int r0 = blockIdx.x * 64;
    const int b  = r0 >> 11;            // 64-row block never crosses a batch

#pragma unroll
    for (int u = 0; u < 4; ++u) {
        const int idx = t + 256 * u;            // float4 index 0..1023
        const int rr = idx >> 4, kk = (idx & 15) * 4;
        *(float4*)&xq_lds[rr][kk] = *(const float4*)(qx + (size_t)(r0 + rr) * HID + kk);
        *(float4*)&xh_lds[rr][kk] = *(const float4*)(hs + (size_t)(r0 + rr) * HID + kk);
    }
    __syncthreads();

    const int c = t & 63, w = t >> 6;
    const int rw = w * 16;                        // wave's 16 rows
    const int h = c >> 5, d = c & 31;
    const size_t obase = ((size_t)((b * 2 + h) * SEQ) + (r0 & 2047) + rw) * 32 + d;

    // ---------------- phase Q (hi/lo) ----------------
    {
        float4 wr[16];
#pragma unroll
        for (int i = 0; i < 16; ++i) wr[i] = *(const float4*)(Wq + c * 64 + 4 * i);
        const float bc = bq[c];
        f32x4 acc[16];
#pragma unroll
        for (int r = 0; r < 16; ++r) acc[r] = (f32x4){0.f, 0.f, 0.f, 0.f};
#pragma unroll
        for (int k4 = 0; k4 < 16; ++k4) {
#pragma unroll
            for (int r = 0; r < 16; ++r) {
                const float4 x4 = *(const float4*)&xq_lds[rw + r][k4 * 4];  // bcast
                acc[r][0] += x4.x * wr[k4].x; acc[r][1] += x4.y * wr[k4].y;
                acc[r][2] += x4.z * wr[k4].z; acc[r][3] += x4.w * wr[k4].w;
            }
        }
#pragma unroll
        for (int r = 0; r < 16; ++r) {
            const float v = (acc[r][0] + acc[r][1] + acc[r][2] + acc[r][3] + bc) * QSCALE;
            const ushort hv = f2bf(v);
            q_hi[obase + (size_t)r * 32] = hv;
            q_lo[obase + (size_t)r * 32] = f2bf(v - bf2f(hv));
        }
    }
    // ---------------- phase K (hi only) ----------------
    {
        float4 wr[16];
#pragma unroll
        for (int i = 0; i < 16; ++i) wr[i] = *(const float4*)(Wk + c * 64 + 4 * i);
        const float bc = bk[c];
        f32x4 acc[16];
#pragma unroll
        for (int r = 0; r < 16; ++r) acc[r] = (f32x4){0.f, 0.f, 0.f, 0.f};
#pragma unroll
        for (int k4 = 0; k4 < 16; ++k4) {
#pragma unroll
            for (int r = 0; r < 16; ++r) {
                const float4 x4 = *(const float4*)&xh_lds[rw + r][k4 * 4];
                acc[r][0] += x4.x * wr[k4].x; acc[r][1] += x4.y * wr[k4].y;
                acc[r][2] += x4.z * wr[k4].z; acc[r][3] += x4.w * wr[k4].w;
            }
        }
#pragma unroll
        for (int r = 0; r < 16; ++r) {
            const float v = acc[r][0] + acc[r][1] + acc[r][2] + acc[r][3] + bc;
            k_hi[obase + (size_t)r * 32] = f2bf(v);
        }
    }
    // ---------------- phase V (hi only, transposed) ----------------
    {
        float4 wr[16];
#pragma unroll
        for (int i = 0; i < 16; ++i) wr[i] = *(const float4*)(Wv + c * 64 + 4 * i);
        const float bc = bv[c];
        f32x4 acc[16];
#pragma unroll
        for (int r = 0; r < 16; ++r) acc[r] = (f32x4){0.f, 0.f, 0.f, 0.f};
#pragma unroll
        for (int k4 = 0; k4 < 16; ++k4) {
#pragma unroll
            for (int r = 0; r < 16; ++r) {
                const float4 x4 = *(const float4*)&xq_lds[rw + r][k4 * 4];  // v uses qx!
                acc[r][0] += x4.x * wr[k4].x; acc[r][1] += x4.y * wr[k4].y;
                acc[r][2] += x4.z * wr[k4].z; acc[r][3] += x4.w * wr[k4].w;
            }
        }
#pragma unroll
        for (int r = 0; r < 16; ++r)
            vbuf[rw + r][c] = acc[r][0] + acc[r][1] + acc[r][2] + acc[r][3] + bc;
    }
    __syncthreads();

    // V transpose: lane c -> (h2,d2) column; 2 groups of 8 consecutive rows
#pragma unroll
    for (int g = 0; g < 2; ++g) {
        const int row8 = (g * 4 + w) * 8;
        bf16x8 hi8;
#pragma unroll
        for (int e = 0; e < 8; ++e) hi8[e] = (short)f2bf(vbuf[row8 + e][c]);
        const size_t vo = ((size_t)((b * 2 + h) * 32) + d) * SEQ + (r0 & 2047) + row8;
        *reinterpret_cast<bf16x8*>(vt_hi + vo) = hi8;
    }
}

// ---------------------------------------------------------------------------
// Kernel 2 (v5): fused attention.
//   Block = 256 threads (4 waves) = one (slice, 32-q-row) block; grid 1024
//   -> 4 blocks/CU (16 waves/CU, 50% occupancy; round-4 was grid-limited to 2).
//   Wave w owns cols [w*512, (w+1)*512) for both 16-row tiles (rt=0,1).
//   K/V fragments register-prefetched one iteration ahead (latency hiding).
//   p staged in bank-swizzled LDS (f32) -> probs written as FULL 128-B lines
//   via nontemporal float4 stores (no L2 pollution / no partial-line RMW).
//   PV A-frags rebuilt from pstage via v_cvt_pk_bf16_f32.
// ---------------------------------------------------------------------------
__global__ __launch_bounds__(256, 4)
void attn_kernel(const ushort* __restrict__ q_hi, const ushort* __restrict__ q_lo,
                 const ushort* __restrict__ k_hi, const ushort* __restrict__ vt_hi,
                 float* __restrict__ d_out)
{
    __shared__ float z_buf[4][32];
    __shared__ __align__(16) float ctx_buf[4][32][32];   // 16 KB
    __shared__ __align__(16) float pstage[4][512];       // 8 KB, wave-private

    // XCD-aware swizzle: 1024 blocks -> 128 consecutive per XCD = 2 slices
    const int bid   = blockIdx.x;
    const int swz   = (bid & 7) * 128 + (bid >> 3);
    const int slice = swz >> 6;          // 0..15 == b*2 + h
    const int qb    = swz & 63;
    const int bb = slice >> 1, hh = slice & 1;
    const int q0 = qb * 32;

    const int tid  = threadIdx.x;
    const int w    = tid >> 6, lane = tid & 63;
    const int lg   = lane >> 4, li = lane & 15;   // frag: i/j = li, k = 8*lg+e
    const int cq0  = w * 512;                     // wave's column quarter

    // A-fragments (q) for the block's 2 row-tiles
    bf16x8 aqh[2], aql[2];
#pragma unroll
    for (int rt = 0; rt < 2; ++rt) {
        const size_t qoff = ((size_t)slice * SEQ + q0 + rt * 16 + li) * 32 + lg * 8;
        aqh[rt] = *reinterpret_cast<const bf16x8*>(q_hi + qoff);
        aql[rt] = *reinterpret_cast<const bf16x8*>(q_lo + qoff);
    }

    const size_t kbase = (size_t)slice * SEQ * 32;
    const size_t vbase = (size_t)slice * 32 * SEQ;

    // K fragment for a 16-col tile j16 (0..31 within quarter)
    auto Kfrag = [&](int j16) {
        return *reinterpret_cast<const bf16x8*>(
            k_hi + kbase + (size_t)(cq0 + j16 * 16 + li) * 32 + lg * 8);
    };
    // V fragment for a 32-col chunk c2, d-tile dt
    auto Vfrag = [&](int c2, int dt) {
        return *reinterpret_cast<const bf16x8*>(
            vt_hi + vbase + (size_t)(dt * 16 + li) * SEQ + cq0 + c2 * 32 + lg * 8);
    };

    // ------------------- pass 1: row sums Z (prefetched) -------------------
    float zacc[8];
#pragma unroll
    for (int i = 0; i < 8; ++i) zacc[i] = 0.f;
    {
        bf16x8 bh = Kfrag(0);
#pragma unroll 2
        for (int ct = 0; ct < 32; ++ct) {
            const bf16x8 bn = Kfrag(ct < 31 ? ct + 1 : 31);
#pragma unroll
            for (int rt = 0; rt < 2; ++rt) {
                f32x4 acc = {0.f, 0.f, 0.f, 0.f};
                acc = __builtin_amdgcn_mfma_f32_16x16x32_bf16(aqh[rt], bh, acc, 0, 0, 0);
                acc = __builtin_amdgcn_mfma_f32_16x16x32_bf16(aql[rt], bh, acc, 0, 0, 0);
#pragma unroll
                for (int r = 0; r < 4; ++r)
                    zacc[rt * 4 + r] += __builtin_amdgcn_exp2f(acc[r]);
            }
            bh = bn;
        }
    }
#pragma unroll
    for (int m = 1; m < 16; m <<= 1) {
#pragma unroll
        for (int i = 0; i < 8; ++i) zacc[i] += __shfl_xor(zacc[i], m, 64);
    }
    if (li == 0) {
#pragma unroll
        for (int rt = 0; rt < 2; ++rt)
#pragma unroll
            for (int r = 0; r < 4; ++r)
                z_buf[w][rt * 16 + lg * 4 + r] = zacc[rt * 4 + r];
    }
    __syncthreads();
    float rcpz[8];
#pragma unroll
    for (int rt = 0; rt < 2; ++rt)
#pragma unroll
        for (int r = 0; r < 4; ++r) {
            const int row = rt * 16 + lg * 4 + r;
            rcpz[rt * 4 + r] = 1.0f / (z_buf[0][row] + z_buf[1][row] +
                                       z_buf[2][row] + z_buf[3][row]);
        }

    // ------------------- pass 2: probs + PV (prefetched) -------------------
    f32x4 pacc[2][2];
#pragma unroll
    for (int rt = 0; rt < 2; ++rt)
#pragma unroll
        for (int dt = 0; dt < 2; ++dt) pacc[rt][dt] = (f32x4){0.f, 0.f, 0.f, 0.f};

    float* probs = d_out + OUT_ELEMS + ((size_t)slice * SEQ + q0) * SEQ;
    float* ps = &pstage[w][0];

    bf16x8 k0 = Kfrag(0), k1 = Kfrag(1);
    bf16x8 v0 = Vfrag(0, 0), v1 = Vfrag(0, 1);

#pragma unroll 1
    for (int c2 = 0; c2 < 16; ++c2) {
        const int cn = (c2 < 15) ? c2 + 1 : 15;     // prefetch next chunk
        const bf16x8 k0n = Kfrag(2 * cn),     k1n = Kfrag(2 * cn + 1);
        const bf16x8 v0n = Vfrag(cn, 0),      v1n = Vfrag(cn, 1);

        bf16x8 ap[2];
#pragma unroll
        for (int rt = 0; rt < 2; ++rt) {
            f32x4 a0 = {0.f, 0.f, 0.f, 0.f}, a1 = {0.f, 0.f, 0.f, 0.f};
            a0 = __builtin_amdgcn_mfma_f32_16x16x32_bf16(aqh[rt], k0, a0, 0, 0, 0);
            a0 = __builtin_amdgcn_mfma_f32_16x16x32_bf16(aql[rt], k0, a0, 0, 0, 0);
            a1 = __builtin_amdgcn_mfma_f32_16x16x32_bf16(aqh[rt], k1, a1, 0, 0, 0);
            a1 = __builtin_amdgcn_mfma_f32_16x16x32_bf16(aql[rt], k1, a1, 0, 0, 0);
            // p -> swizzled LDS stage (bank-safe: 2 lanes/bank)
#pragma unroll
            for (int r = 0; r < 4; ++r) {
                const int row = lg * 4 + r;
                const float p0 = __builtin_amdgcn_exp2f(a0[r]) * rcpz[rt * 4 + r];
                const float p1 = __builtin_amdgcn_exp2f(a1[r]) * rcpz[rt * 4 + r];
                ps[row * 32 + (li ^ (lg << 3))]        = p0;   // cols [0,16)
                ps[row * 32 + ((16 + li) ^ (lg << 3))] = p1;   // cols [16,32)
            }
            // probs out: full 128-B lines, nontemporal (no L2 pollution)
#pragma unroll
            for (int u = 0; u < 2; ++u) {
                const int fid = lane + 64 * u;       // 0..127 float4 cells
                const int row = fid >> 3, c4 = fid & 7;
                const int pcb = (c4 * 4) ^ (((row >> 2) & 3) << 3);
                const f32x4 pv = *reinterpret_cast<const f32x4*>(&ps[row * 32 + pcb]);
                __builtin_nontemporal_store(pv, reinterpret_cast<f32x4*>(
                    probs + (size_t)(rt * 16 + row) * SEQ + cq0 + c2 * 32 + c4 * 4));
            }
            // PV A-frag: 8 p-values (row li, k-cols lg*8..+7) -> bf16 pack
            const int abase = li * 32 + ((lg ^ ((li >> 2) & 3)) << 3);
            const f32x4 pa = *reinterpret_cast<const f32x4*>(&ps[abase]);
            const f32x4 pb = *reinterpret_cast<const f32x4*>(&ps[abase + 4]);
            u32x4 pk;
            pk[0] = cvt_pk_bf16(pa[0], pa[1]); pk[1] = cvt_pk_bf16(pa[2], pa[3]);
            pk[2] = cvt_pk_bf16(pb[0], pb[1]); pk[3] = cvt_pk_bf16(pb[2], pb[3]);
            ap[rt] = __builtin_bit_cast(bf16x8, pk);
        }
        // PV for this 32-col chunk
#pragma unroll
        for (int rt = 0; rt < 2; ++rt) {
            pacc[rt][0] = __builtin_amdgcn_mfma_f32_16x16x32_bf16(ap[rt], v0, pacc[rt][0], 0, 0, 0);
            pacc[rt][1] = __builtin_amdgcn_mfma_f32_16x16x32_bf16(ap[rt], v1, pacc[rt][1], 0, 0, 0);
        }
        k0 = k0n; k1 = k1n; v0 = v0n; v1 = v1n;
    }

    // partials -> LDS, cross-wave (col-quarter) reduce, write ctx
#pragma unroll
    for (int rt = 0; rt < 2; ++rt)
#pragma unroll
        for (int dt = 0; dt < 2; ++dt)
#pragma unroll
            for (int r = 0; r < 4; ++r)
                ctx_buf[w][rt * 16 + lg * 4 + r][dt * 16 + li] = pacc[rt][dt][r];
    __syncthreads();
    {
        const int row = tid >> 3, dq = tid & 7;      // 32 rows x 8 float4
        float4 s = *reinterpret_cast<const float4*>(&ctx_buf[0][row][dq * 4]);
#pragma unroll
        for (int ww = 1; ww < 4; ++ww) {
            const float4 c = *reinterpret_cast<const float4*>(&ctx_buf[ww][row][dq * 4]);
            s.x += c.x; s.y += c.y; s.z += c.z; s.w += c.w;
        }
        *reinterpret_cast<float4*>(
            d_out + ((size_t)bb * SEQ + q0 + row) * HID + hh * HDIM + dq * 4) = s;
    }
}

// ---------------------------------------------------------------------------
// Kernel 3: output projection, in place over d_out's ctx region.
// ---------------------------------------------------------------------------
__global__ __launch_bounds__(256, 1)
void out_proj_kernel(const float* __restrict__ Wo, const float* __restrict__ bo,
                     float* __restrict__ out)
{
    const int c    = threadIdx.x & 63;
    const int rloc = threadIdx.x >> 6;

    float4 wo[16];
#pragma unroll
    for (int i = 0; i < 16; ++i) wo[i] = *(const float4*)(Wo + c * 64 + 4 * i);
    const float boc = bo[c];

    for (int rg = blockIdx.x; rg < ROWS / 4; rg += gridDim.x) {
        const int row = rg * 4 + rloc;
        const float* x = out + (size_t)row * HID;  // ctx row (wave-uniform addr)
        float a = 0.f;
#pragma unroll
        for (int i = 0; i < 16; ++i) {
            const float4 x4 = *(const float4*)(x + 4 * i);
            a += x4.x * wo[i].x + x4.y * wo[i].y + x4.z * wo[i].z + x4.w * wo[i].w;
        }
        out[(size_t)row * HID + c] = a + boc;
    }
}

// ---------------------------------------------------------------------------
extern "C" void kernel_launch(void* const* d_in, const int* in_sizes, int n_in,
                              void* d_out, int out_size, void* d_ws, size_t ws_size,
                              hipStream_t stream)
{
    const float* hs = (const float*)d_in[0];
    const float* qx = (const float*)d_in[1];
    const float* Wq = (const float*)d_in[2];
    const float* bq = (const float*)d_in[3];
    const float* Wk = (const float*)d_in[4];
    const float* bk = (const float*)d_in[5];
    const float* Wv = (const float*)d_in[6];
    const float* bv = (const float*)d_in[7];
    const float* Wo = (const float*)d_in[8];
    const float* bo = (const float*)d_in[9];
    float* out = (float*)d_out;

    // workspace: 4 bf16 arrays of 16*2048*32 = 1M elements (2 MB) each = 8 MB
    const size_t N = (size_t)16 * SEQ * 32;
    ushort* q_hi  = (ushort*)d_ws;
    ushort* q_lo  = q_hi + N;
    ushort* k_hi  = q_lo + N;
    ushort* vt_hi = k_hi + N;

    qkv_proj_kernel<<<256, 256, 0, stream>>>(hs, qx, Wq, bq, Wk, bk, Wv, bv,
                                             q_hi, q_lo, k_hi, vt_hi);
    attn_kernel<<<1024, 256, 0, stream>>>(q_hi, q_lo, k_hi, vt_hi, out);
    out_proj_kernel<<<512, 256, 0, stream>>>(Wo, bo, out);
}